// Round 12
// baseline (179.178 us; speedup 1.0000x reference)
//
#include <hip/hip_runtime.h>
#include <cstdint>

#define T_DIM 1000
#define B_DIM 64
#define C_DIM 256
#define L_DIM 100
#define S_DIM (2 * L_DIM + 1) /* 201 */
#define CH 32                 /* steps per chunk */
#define NPROD 7               /* producer waves (block = 8 waves) */
#define RPW 5                 /* ceil(CH/NPROD) rows per producer wave */
#define EMW 132               /* emit row: [0..63]=q1 [64..127]=q3 [128]=pb */
#define MEAN_BLOCKS 192       /* 64 b x 3 T-slices; grid = 64+192 = 256 = #CUs */
#define NBLOCKS (B_DIM + MEAN_BLOCKS)

typedef float f32x4 __attribute__((ext_vector_type(4)));

// DPP cross-lane (VALU-rate). wave_shr:1=0x138, row_shr:n=0x110|n,
// row_bcast:15=0x142, row_bcast:31=0x143. bound_ctrl=true -> invalid lanes read 0.
#define DPP_I(x, ctrl) __builtin_amdgcn_update_dpp(0, (x), (ctrl), 0xF, 0xF, true)
#define DPP_F(x, ctrl) __int_as_float(DPP_I(__float_as_int(x), (ctrl)))

// R11 audit: ctc_fused dispatch = 57us but TOTAL = 137us. The ~80us gap is
// outside the main dispatch -- dominated by ctc_finalize: a 1-block kernel on
// an otherwise-IDLE gpu (0.4% util -> min DVFS clock -> its ~15k cycles
// stretch to tens of us). R12: fold finalize into the main kernel via the
// last-block pattern (device-scope counter, G16-sound) -> it runs while the
// clock is hot. Stream: 3 ops -> 2 ops.
#define DSR(dst, addr, OFF) \
    asm volatile("ds_read_b32 %0, %1 offset:" OFF : "=v"(dst) : "v"(addr))
#define ISS(s, OFF) do { DSR(pb##s, apb, OFF); DSR(qa##s, aq1, OFF); DSR(qb##s, aq3, OFF); } while (0)
#define W(N) do { asm volatile("s_waitcnt lgkmcnt(" N ")"); __builtin_amdgcn_sched_barrier(0); } while (0)
#define STP(s) step(pb##s, qa##s, qb##s)
#define SD(s, OFF) do { W("12"); STP(s); ISS(s, OFF); } while (0)

// Wave-wide max of non-negative values; exact, order-independent.
__device__ __forceinline__ float wave_max_dpp(float x) {
    x = fmaxf(x, DPP_F(x, 0x111)); // row_shr:1
    x = fmaxf(x, DPP_F(x, 0x112)); // row_shr:2
    x = fmaxf(x, DPP_F(x, 0x114)); // row_shr:4
    x = fmaxf(x, DPP_F(x, 0x118)); // row_shr:8
    x = fmaxf(x, DPP_F(x, 0x142)); // row_bcast:15
    x = fmaxf(x, DPP_F(x, 0x143)); // row_bcast:31 -> lane 63 has wave max
    return __int_as_float(__builtin_amdgcn_readlane(__float_as_int(x), 63));
}

// Single fused kernel, 512-thread blocks; grid = 256 = #CUs.
//   blocks [0,B): CTC alpha recursion (R11 form: compact conflict-free emit).
//   blocks [B, B+192): mean pass (R11 form, f32x4).
//   LAST block to finish (counter==255): runs the focal/loss reduction and
//   writes out[0]. All math identical to the old ctc_finalize kernel.
__global__ __launch_bounds__(512, 1) void ctc_fused(
        const float* __restrict__ lp,       // (T,B,C)
        const int* __restrict__ tgt,        // (B*L,)
        const int* __restrict__ il,         // (B,)
        const int* __restrict__ tl,         // (B,)
        float* __restrict__ ws,             // [B*C mean][B loss][1 counter]
        float* __restrict__ out) {          // scalar
    float* ws_mean = ws;
    float* ws_loss = ws + B_DIM * C_DIM;
    unsigned int* ctr = (unsigned int*)(ws + B_DIM * C_DIM + B_DIM);

    __shared__ int lastflag;
    const int blk = blockIdx.x;
    const int tid = threadIdx.x;
    const uint32_t rstride = B_DIM * C_DIM;

    if (blk >= B_DIM) {
        // ---- mean pass: block=(b, slice of T in {336,336,328}); 8 waves ----
        __shared__ float sums[8][C_DIM];
        const int mb = blk - B_DIM;
        const int b = mb / 3;
        const int slice = mb % 3;
        const int start = slice * 336;
        const int end = (slice == 2) ? T_DIM : start + 336; // (end-start)%8==0
        const int lane = tid & 63;
        const int wv = tid >> 6;                // 0..7
        const float* p = lp + (size_t)b * C_DIM + (lane << 2);
        f32x4 s = {0.f, 0.f, 0.f, 0.f};
        for (int t = start + wv; t < end; t += 8) {
            f32x4 v = *(const f32x4*)(p + (size_t)t * rstride);
            s.x += __expf(v.x); s.y += __expf(v.y);
            s.z += __expf(v.z); s.w += __expf(v.w);
        }
        *(f32x4*)&sums[wv][lane << 2] = s;
        __syncthreads();
        if (tid < C_DIM) {
            const int c = tid;
            float tot = sums[0][c] + sums[1][c] + sums[2][c] + sums[3][c]
                      + sums[4][c] + sums[5][c] + sums[6][c] + sums[7][c];
            atomicAdd(&ws_mean[b * C_DIM + c], tot * (1.0f / T_DIM));
        }
    } else {
        // ---- CTC pass (R11 form, unchanged math) ----
        __shared__ __align__(16) float emit[2][CH][EMW]; // compact exp'd

        const int lane = tid & 63;
        const int wave = tid >> 6;
        const int b = blk;
        const int* trow = tgt + b * L_DIM;
        const int ilen = il[b];
        const int tlen = tl[b];

        const int i1 = 2 * lane;
        const int i3 = 2 * lane + 1;
        const int c1 = (i1 < L_DIM) ? trow[i1] : 0;
        const int c3 = (i3 < L_DIM) ? trow[i3] : 0;
        const int c1m = (i1 >= 1 && i1 - 1 < L_DIM) ? trow[i1 - 1] : -1;
        const float m1 = ((i1 >= 1) && (c1 != c1m)) ? 1.0f : 0.0f;
        const float m3 = (c3 != c1) ? 1.0f : 0.0f;

        // invalid states (s >= S) must be zeroed at each renorm
        const float f0 = (4 * lane + 0 < S_DIM) ? 1.0f : 0.0f;
        const float f1 = (4 * lane + 1 < S_DIM) ? 1.0f : 0.0f;
        const float f2 = (4 * lane + 2 < S_DIM) ? 1.0f : 0.0f;
        const float f3 = (4 * lane + 3 < S_DIM) ? 1.0f : 0.0f;

        const float* base = lp + (size_t)b * C_DIM;

        // t=0 init (bit-identical)
        float a0 = 0.f, a1 = 0.f, a2 = 0.f, a3 = 0.f;
        {
            float i0 = __expf(base[0]);
            float i1v = __expf(base[c1]);
            if (lane == 0 && wave == 0) { a0 = i0; a1 = i1v; }
        }
        float ls = 0.f;

        // producer: per row, 3 scattered COMPILER global loads, single anchor,
        // exp only needed values, conflict-free b32 emit writes.
        auto produce = [&](int cc) {
            const int p = cc & 1;
            const int tstart = 1 + cc * CH;
            const int w = wave - 1;
            float v1[RPW], v3[RPW], v0[RPW];
#pragma unroll
            for (int k = 0; k < RPW; ++k) {
                const int d = w + NPROD * k;
                if (d < CH) {
                    int t = tstart + d; t = (t < ilen) ? t : (ilen - 1);
                    const float* rp = base + (size_t)t * rstride;
                    v1[k] = rp[c1];
                    v3[k] = rp[c3];
                    v0[k] = rp[0];
                } else {
                    v1[k] = 0.f; v3[k] = 0.f; v0[k] = 0.f;
                }
            }
            asm volatile("" : "+v"(v1[0]), "+v"(v1[1]), "+v"(v1[2]), "+v"(v1[3]), "+v"(v1[4]),
                              "+v"(v3[0]), "+v"(v3[1]), "+v"(v3[2]), "+v"(v3[3]), "+v"(v3[4]),
                              "+v"(v0[0]), "+v"(v0[1]), "+v"(v0[2]), "+v"(v0[3]), "+v"(v0[4]));
#pragma unroll
            for (int k = 0; k < RPW; ++k) {
                const int d = w + NPROD * k;
                if (d < CH) {
                    const float e1 = __expf(v1[k]);
                    const float e3 = __expf(v3[k]);
                    const float e0 = __expf(v0[k]);
                    emit[p][d][lane] = e1;
                    emit[p][d][64 + lane] = e3;
                    if (lane == 0) emit[p][d][128] = e0;
                }
            }
        };

        // consumer step: inputs already exp'd; absmax must stay 96.0.
        auto step = [&](float pb, float p1e, float p3e) {
            const float p3 = DPP_F(a3, 0x138); // prev lane's a3; lane0 -> 0
            const float a01 = a0 + a1;
            const float n0 = (a0 + p3) * pb;
            const float n1 = fmaf(m1, p3, a01) * p1e;
            const float n2 = (a2 + a1) * pb;
            const float n3 = (fmaf(m3, a1, a2) + a3) * p3e;
            a0 = n0; a1 = n1; a2 = n2; a3 = n3;
        };

#define RENORM() do {                                                       \
        a0 *= f0; a1 *= f1; a2 *= f2; a3 *= f3;                             \
        const float mx = wave_max_dpp(fmaxf(fmaxf(a0, a1), fmaxf(a2, a3))); \
        const float inv = __builtin_amdgcn_rcpf(mx);                        \
        ls -= __logf(inv);                                                  \
        a0 *= inv; a1 *= inv; a2 *= inv; a3 *= inv;                         \
    } while (0)

        // consume chunk cc; renorm set {t%8==0, t<=992} (established).
        auto consume = [&](int cc) {
            const int p = cc & 1;
            const int tstart = 1 + cc * CH;
            if (tstart + CH <= ilen) {
                const uint32_t lbase =
                    (uint32_t)(uintptr_t)(&emit[0][0][0]) + (uint32_t)(p * (CH * EMW * 4));
                uint32_t apb = lbase + 512;                    // emit[p][d][128]
                uint32_t aq1 = lbase + ((uint32_t)lane << 2);  // emit[p][d][lane]
                uint32_t aq3 = aq1 + 256;                      // emit[p][d][64+lane]
                float pb0, pb1, pb2, pb3, pb4;
                float qa0, qa1, qa2, qa3, qa4;
                float qb0, qb1, qb2, qb3, qb4;
                ISS(0, "0"); ISS(1, "528"); ISS(2, "1056"); ISS(3, "1584"); ISS(4, "2112");
                SD(0, "2640");              // d=0
                SD(1, "3168");              // d=1
                SD(2, "3696");              // d=2
                SD(3, "4224");              // d=3
                SD(4, "4752");              // d=4
                SD(0, "5280");              // d=5
                SD(1, "5808");              // d=6
                SD(2, "6336"); RENORM();    // d=7
                SD(3, "6864");              // d=8
                SD(4, "7392");              // d=9
                SD(0, "7920");              // d=10
                SD(1, "8448");              // d=11
                SD(2, "8976");              // d=12
                SD(3, "9504");              // d=13
                SD(4, "10032");             // d=14
                SD(0, "10560"); RENORM();   // d=15
                SD(1, "11088");             // d=16
                SD(2, "11616");             // d=17
                SD(3, "12144");             // d=18
                SD(4, "12672");             // d=19
                SD(0, "13200");             // d=20
                SD(1, "13728");             // d=21
                SD(2, "14256");             // d=22
                SD(3, "14784"); RENORM();   // d=23
                SD(4, "15312");             // d=24
                SD(0, "15840");             // d=25
                SD(1, "16368");             // d=26 (issues d=31)
                W("12"); STP(2);            // d=27
                W("9");  STP(3);            // d=28
                W("6");  STP(4);            // d=29
                W("3");  STP(0);            // d=30
                W("0");  STP(1); RENORM();  // d=31
            } else {
                // tail chunk (7 steps for T=1000): point-of-use form
#pragma unroll
                for (int d = 0; d < CH; ++d) {
                    if (tstart + d < ilen) {
                        step(emit[p][d][128], emit[p][d][lane], emit[p][d][64 + lane]);
                        if ((d & 7) == 7) RENORM();
                    }
                }
            }
        };

        const int nchunks = (ilen - 1 + CH - 1) / CH;
        if (wave != 0) produce(0);
        __syncthreads();
        if (wave == 0) __builtin_amdgcn_s_setprio(1);
        for (int c = 0; c < nchunks; ++c) {
            if (wave != 0) produce(c + 1);
            else consume(c);
            __syncthreads();
        }
        if (wave == 0) __builtin_amdgcn_s_setprio(0);
#undef RENORM

        if (wave == 0) {
            // final: ll = log(alpha[2tl] + alpha[2tl-1]) + ls
            const int s_hi = 2 * tlen;
            const int s_lo = 2 * tlen - 1;
            const int slot_hi = s_hi & 3, lane_hi = min(s_hi >> 2, 63);
            const int slot_lo = s_lo & 3, lane_lo = min(s_lo >> 2, 63);
            float chv = (slot_hi == 0) ? a0 : (slot_hi == 1) ? a1 : (slot_hi == 2) ? a2 : a3;
            float clv = (slot_lo == 0) ? a0 : (slot_lo == 1) ? a1 : (slot_lo == 2) ? a2 : a3;
            const float vh = __shfl(chv, lane_hi, 64);
            const float vl = __shfl(clv, lane_lo, 64);
            if (lane == 0) {
                const float s = vh + vl;
                const float loss = (s > 0.f) ? -(__logf(s) + ls) : 0.0f; // zero_infinity
                ws_loss[b] = loss;
            }
        }
    }

    // ---- last-block finalize (replaces the ctc_finalize kernel) ----
    __threadfence();                              // publish ws_loss / ws_mean
    if (tid == 0) {
        const unsigned int old = atomicAdd(ctr, 1u);   // device-scope
        lastflag = (old == NBLOCKS - 1) ? 1 : 0;
    }
    __syncthreads();
    if (!lastflag) return;
    __threadfence();                              // acquire: all blocks' writes

    // out = (sum_j focal_j / (B*L)) * (sum_b loss_b / B)   [identical math]
    {
        float fsum = 0.f, lsum = 0.f;
        if (tid < 256) {
#pragma unroll
            for (int k = 0; k < (B_DIM * L_DIM) / 256; ++k) {
                const int j = tid + k * 256;
                const int b2 = j / L_DIM;
                const int c2 = tgt[j];
                const float p = ws_mean[b2 * C_DIM + c2];
                const float w2 = 1.0f - p;
                fsum += w2 * w2;
            }
            lsum = (tid < B_DIM) ? ws_loss[tid] : 0.f;
        }
#pragma unroll
        for (int off = 32; off > 0; off >>= 1) {
            fsum += __shfl_down(fsum, off, 64);
            lsum += __shfl_down(lsum, off, 64);
        }
        __shared__ float sf[8], sl[8];
        const int w2 = tid >> 6;
        if ((tid & 63) == 0) { sf[w2] = fsum; sl[w2] = lsum; }
        __syncthreads();
        if (tid == 0) {
            const float F = sf[0] + sf[1] + sf[2] + sf[3]
                          + sf[4] + sf[5] + sf[6] + sf[7];   // waves 4-7 = 0
            const float Lo = sl[0] + sl[1] + sl[2] + sl[3]
                           + sl[4] + sl[5] + sl[6] + sl[7];
            out[0] = (F / (float)(B_DIM * L_DIM)) * (Lo / (float)B_DIM);
        }
    }
}

extern "C" void kernel_launch(void* const* d_in, const int* in_sizes, int n_in,
                              void* d_out, int out_size, void* d_ws, size_t ws_size,
                              hipStream_t stream) {
    const float* lp = (const float*)d_in[0];
    const int* tgt = (const int*)d_in[1];
    const int* il = (const int*)d_in[2];
    const int* tl = (const int*)d_in[3];
    float* ws = (float*)d_ws;   // [B*C mean][B loss][1 counter]

    hipMemsetAsync(ws, 0, (B_DIM * C_DIM + B_DIM + 1) * sizeof(float), stream);
    ctc_fused<<<dim3(NBLOCKS), dim3(512), 0, stream>>>(
        lp, tgt, il, tl, ws, (float*)d_out);
}

// Round 13
// 135.478 us; speedup vs baseline: 1.3226x; 1.3226x over previous
//
#include <hip/hip_runtime.h>
#include <cstdint>

#define T_DIM 1000
#define B_DIM 64
#define C_DIM 256
#define L_DIM 100
#define S_DIM (2 * L_DIM + 1) /* 201 */
#define CH 32                 /* steps per chunk */
#define NPROD 7               /* producer waves (block = 8 waves) */
#define RPW 5                 /* ceil(CH/NPROD) rows per producer wave */
#define EMW 132               /* emit row: [0..63]=q1 [64..127]=q3 [128]=pb */
#define NBLK (2 * B_DIM)      /* 64 CTC + 64 mean blocks */

typedef float f32x4 __attribute__((ext_vector_type(4)));

// DPP cross-lane (VALU-rate). wave_shr:1=0x138, row_shr:n=0x110|n,
// row_bcast:15=0x142, row_bcast:31=0x143. bound_ctrl=true -> invalid lanes read 0.
#define DPP_I(x, ctrl) __builtin_amdgcn_update_dpp(0, (x), (ctrl), 0xF, 0xF, true)
#define DPP_F(x, ctrl) __int_as_float(DPP_I(__float_as_int(x), (ctrl)))

// R12 lesson: per-block __threadfence = device-scope L2 writeback x 256 blocks
// -> +55us. R13 protocol: data via device-scope atomicAdd (G12: default
// scope), completion via tid0's own s_waitcnt vmcnt(0) (waits its OWN atomic
// only, no cache writeback), last-arriver reads scalars with atomicAdd(p,0).
#define DSR(dst, addr, OFF) \
    asm volatile("ds_read_b32 %0, %1 offset:" OFF : "=v"(dst) : "v"(addr))
#define ISS(s, OFF) do { DSR(pb##s, apb, OFF); DSR(qa##s, aq1, OFF); DSR(qb##s, aq3, OFF); } while (0)
#define W(N) do { asm volatile("s_waitcnt lgkmcnt(" N ")"); __builtin_amdgcn_sched_barrier(0); } while (0)
#define STP(s) step(pb##s, qa##s, qb##s)
#define SD(s, OFF) do { W("12"); STP(s); ISS(s, OFF); } while (0)

// Wave-wide max of non-negative values; exact, order-independent.
__device__ __forceinline__ float wave_max_dpp(float x) {
    x = fmaxf(x, DPP_F(x, 0x111)); // row_shr:1
    x = fmaxf(x, DPP_F(x, 0x112)); // row_shr:2
    x = fmaxf(x, DPP_F(x, 0x114)); // row_shr:4
    x = fmaxf(x, DPP_F(x, 0x118)); // row_shr:8
    x = fmaxf(x, DPP_F(x, 0x142)); // row_bcast:15
    x = fmaxf(x, DPP_F(x, 0x143)); // row_bcast:31 -> lane 63 has wave max
    return __int_as_float(__builtin_amdgcn_readlane(__float_as_int(x), 63));
}

// Single kernel, 128 blocks x 512 threads (1 block/CU, half the CUs).
//   blocks [0,B): CTC alpha recursion (R11 form, bit-identical values);
//                 consumer lane0 atomicAdds loss into ws[1] (Lo).
//   blocks [B,2B): per-sample mean: full-T channel means in LDS (no global
//                 round-trip), then that sample's focal sum -> atomicAdd ws[0].
//   last arriver (counter ws[2]): out = (F/(B*L)) * (Lo/B). No fences.
__global__ __launch_bounds__(512, 1) void ctc_fused(
        const float* __restrict__ lp,       // (T,B,C)
        const int* __restrict__ tgt,        // (B*L,)
        const int* __restrict__ il,         // (B,)
        const int* __restrict__ tl,         // (B,)
        float* __restrict__ ws,             // [0]=F [1]=Lo [2]=counter
        float* __restrict__ out) {          // scalar
    const int blk = blockIdx.x;
    const int tid = threadIdx.x;
    const uint32_t rstride = B_DIM * C_DIM;

    if (blk >= B_DIM) {
        // ---- mean + focal pass: one block per sample b ----
        __shared__ float sums[8][C_DIM];
        __shared__ float meanp[C_DIM];
        __shared__ float focal[128];
        const int b = blk - B_DIM;
        const int lane = tid & 63;
        const int wv = tid >> 6;                 // 0..7
        const float* p = lp + (size_t)b * C_DIM + (lane << 2);
        f32x4 s = {0.f, 0.f, 0.f, 0.f};
#pragma unroll 5
        for (int t = wv; t < T_DIM; t += 8) {    // 125 rows per wave
            f32x4 v = *(const f32x4*)(p + (size_t)t * rstride);
            s.x += __expf(v.x); s.y += __expf(v.y);
            s.z += __expf(v.z); s.w += __expf(v.w);
        }
        *(f32x4*)&sums[wv][lane << 2] = s;
        __syncthreads();
        if (tid < C_DIM) {
            const float tot = sums[0][tid] + sums[1][tid] + sums[2][tid] + sums[3][tid]
                            + sums[4][tid] + sums[5][tid] + sums[6][tid] + sums[7][tid];
            meanp[tid] = tot * (1.0f / T_DIM);
        }
        __syncthreads();
        if (tid < L_DIM) {
            const float pv = meanp[tgt[b * L_DIM + tid]];
            const float w = 1.0f - pv;
            focal[tid] = w * w;
        }
        __syncthreads();
        if (tid < 64) {
            float fs = focal[tid] + ((tid + 64 < L_DIM) ? focal[tid + 64] : 0.f);
#pragma unroll
            for (int off = 32; off > 0; off >>= 1) fs += __shfl_down(fs, off, 64);
            if (tid == 0) atomicAdd(&ws[0], fs);  // device-scope
        }
    } else {
        // ---- CTC pass (R11 form, unchanged math) ----
        __shared__ __align__(16) float emit[2][CH][EMW]; // compact exp'd

        const int lane = tid & 63;
        const int wave = tid >> 6;
        const int b = blk;
        const int* trow = tgt + b * L_DIM;
        const int ilen = il[b];
        const int tlen = tl[b];

        const int i1 = 2 * lane;
        const int i3 = 2 * lane + 1;
        const int c1 = (i1 < L_DIM) ? trow[i1] : 0;
        const int c3 = (i3 < L_DIM) ? trow[i3] : 0;
        const int c1m = (i1 >= 1 && i1 - 1 < L_DIM) ? trow[i1 - 1] : -1;
        const float m1 = ((i1 >= 1) && (c1 != c1m)) ? 1.0f : 0.0f;
        const float m3 = (c3 != c1) ? 1.0f : 0.0f;

        // invalid states (s >= S) must be zeroed at each renorm
        const float f0 = (4 * lane + 0 < S_DIM) ? 1.0f : 0.0f;
        const float f1 = (4 * lane + 1 < S_DIM) ? 1.0f : 0.0f;
        const float f2 = (4 * lane + 2 < S_DIM) ? 1.0f : 0.0f;
        const float f3 = (4 * lane + 3 < S_DIM) ? 1.0f : 0.0f;

        const float* base = lp + (size_t)b * C_DIM;

        // t=0 init (bit-identical)
        float a0 = 0.f, a1 = 0.f, a2 = 0.f, a3 = 0.f;
        {
            float i0 = __expf(base[0]);
            float i1v = __expf(base[c1]);
            if (lane == 0 && wave == 0) { a0 = i0; a1 = i1v; }
        }
        float ls = 0.f;

        // producer: per row, 3 scattered COMPILER global loads, single anchor,
        // exp only needed values, conflict-free b32 emit writes.
        auto produce = [&](int cc) {
            const int p = cc & 1;
            const int tstart = 1 + cc * CH;
            const int w = wave - 1;
            float v1[RPW], v3[RPW], v0[RPW];
#pragma unroll
            for (int k = 0; k < RPW; ++k) {
                const int d = w + NPROD * k;
                if (d < CH) {
                    int t = tstart + d; t = (t < ilen) ? t : (ilen - 1);
                    const float* rp = base + (size_t)t * rstride;
                    v1[k] = rp[c1];
                    v3[k] = rp[c3];
                    v0[k] = rp[0];
                } else {
                    v1[k] = 0.f; v3[k] = 0.f; v0[k] = 0.f;
                }
            }
            asm volatile("" : "+v"(v1[0]), "+v"(v1[1]), "+v"(v1[2]), "+v"(v1[3]), "+v"(v1[4]),
                              "+v"(v3[0]), "+v"(v3[1]), "+v"(v3[2]), "+v"(v3[3]), "+v"(v3[4]),
                              "+v"(v0[0]), "+v"(v0[1]), "+v"(v0[2]), "+v"(v0[3]), "+v"(v0[4]));
#pragma unroll
            for (int k = 0; k < RPW; ++k) {
                const int d = w + NPROD * k;
                if (d < CH) {
                    const float e1 = __expf(v1[k]);
                    const float e3 = __expf(v3[k]);
                    const float e0 = __expf(v0[k]);
                    emit[p][d][lane] = e1;
                    emit[p][d][64 + lane] = e3;
                    if (lane == 0) emit[p][d][128] = e0;
                }
            }
        };

        // consumer step: inputs already exp'd; absmax must stay 96.0.
        auto step = [&](float pb, float p1e, float p3e) {
            const float p3 = DPP_F(a3, 0x138); // prev lane's a3; lane0 -> 0
            const float a01 = a0 + a1;
            const float n0 = (a0 + p3) * pb;
            const float n1 = fmaf(m1, p3, a01) * p1e;
            const float n2 = (a2 + a1) * pb;
            const float n3 = (fmaf(m3, a1, a2) + a3) * p3e;
            a0 = n0; a1 = n1; a2 = n2; a3 = n3;
        };

#define RENORM() do {                                                       \
        a0 *= f0; a1 *= f1; a2 *= f2; a3 *= f3;                             \
        const float mx = wave_max_dpp(fmaxf(fmaxf(a0, a1), fmaxf(a2, a3))); \
        const float inv = __builtin_amdgcn_rcpf(mx);                        \
        ls -= __logf(inv);                                                  \
        a0 *= inv; a1 *= inv; a2 *= inv; a3 *= inv;                         \
    } while (0)

        // consume chunk cc; renorm set {t%8==0, t<=992} (established).
        auto consume = [&](int cc) {
            const int p = cc & 1;
            const int tstart = 1 + cc * CH;
            if (tstart + CH <= ilen) {
                const uint32_t lbase =
                    (uint32_t)(uintptr_t)(&emit[0][0][0]) + (uint32_t)(p * (CH * EMW * 4));
                uint32_t apb = lbase + 512;                    // emit[p][d][128]
                uint32_t aq1 = lbase + ((uint32_t)lane << 2);  // emit[p][d][lane]
                uint32_t aq3 = aq1 + 256;                      // emit[p][d][64+lane]
                float pb0, pb1, pb2, pb3, pb4;
                float qa0, qa1, qa2, qa3, qa4;
                float qb0, qb1, qb2, qb3, qb4;
                ISS(0, "0"); ISS(1, "528"); ISS(2, "1056"); ISS(3, "1584"); ISS(4, "2112");
                SD(0, "2640");              // d=0
                SD(1, "3168");              // d=1
                SD(2, "3696");              // d=2
                SD(3, "4224");              // d=3
                SD(4, "4752");              // d=4
                SD(0, "5280");              // d=5
                SD(1, "5808");              // d=6
                SD(2, "6336"); RENORM();    // d=7
                SD(3, "6864");              // d=8
                SD(4, "7392");              // d=9
                SD(0, "7920");              // d=10
                SD(1, "8448");              // d=11
                SD(2, "8976");              // d=12
                SD(3, "9504");              // d=13
                SD(4, "10032");             // d=14
                SD(0, "10560"); RENORM();   // d=15
                SD(1, "11088");             // d=16
                SD(2, "11616");             // d=17
                SD(3, "12144");             // d=18
                SD(4, "12672");             // d=19
                SD(0, "13200");             // d=20
                SD(1, "13728");             // d=21
                SD(2, "14256");             // d=22
                SD(3, "14784"); RENORM();   // d=23
                SD(4, "15312");             // d=24
                SD(0, "15840");             // d=25
                SD(1, "16368");             // d=26 (issues d=31)
                W("12"); STP(2);            // d=27
                W("9");  STP(3);            // d=28
                W("6");  STP(4);            // d=29
                W("3");  STP(0);            // d=30
                W("0");  STP(1); RENORM();  // d=31
            } else {
                // tail chunk (7 steps for T=1000): point-of-use form
#pragma unroll
                for (int d = 0; d < CH; ++d) {
                    if (tstart + d < ilen) {
                        step(emit[p][d][128], emit[p][d][lane], emit[p][d][64 + lane]);
                        if ((d & 7) == 7) RENORM();
                    }
                }
            }
        };

        const int nchunks = (ilen - 1 + CH - 1) / CH;
        if (wave != 0) produce(0);
        __syncthreads();
        if (wave == 0) __builtin_amdgcn_s_setprio(1);
        for (int c = 0; c < nchunks; ++c) {
            if (wave != 0) produce(c + 1);
            else consume(c);
            __syncthreads();
        }
        if (wave == 0) __builtin_amdgcn_s_setprio(0);
#undef RENORM

        if (wave == 0) {
            // final: ll = log(alpha[2tl] + alpha[2tl-1]) + ls
            const int s_hi = 2 * tlen;
            const int s_lo = 2 * tlen - 1;
            const int slot_hi = s_hi & 3, lane_hi = min(s_hi >> 2, 63);
            const int slot_lo = s_lo & 3, lane_lo = min(s_lo >> 2, 63);
            float chv = (slot_hi == 0) ? a0 : (slot_hi == 1) ? a1 : (slot_hi == 2) ? a2 : a3;
            float clv = (slot_lo == 0) ? a0 : (slot_lo == 1) ? a1 : (slot_lo == 2) ? a2 : a3;
            const float vh = __shfl(chv, lane_hi, 64);
            const float vl = __shfl(clv, lane_lo, 64);
            if (lane == 0) {
                const float s = vh + vl;
                const float loss = (s > 0.f) ? -(__logf(s) + ls) : 0.0f; // zero_infinity
                atomicAdd(&ws[1], loss);   // device-scope
            }
        }
    }

    // ---- fence-free last-arriver finalize (tid0 only) ----
    if (tid == 0) {
        asm volatile("s_waitcnt vmcnt(0)"); // my own data-atomic is complete
        unsigned int* ctr = (unsigned int*)ws + 2;
        const unsigned int old = atomicAdd(ctr, 1u);
        if (old == NBLK - 1) {
            const float F = atomicAdd(&ws[0], 0.0f);   // atomic read
            const float Lo = atomicAdd(&ws[1], 0.0f);  // atomic read
            out[0] = (F / (float)(B_DIM * L_DIM)) * (Lo / (float)B_DIM);
        }
    }
}

extern "C" void kernel_launch(void* const* d_in, const int* in_sizes, int n_in,
                              void* d_out, int out_size, void* d_ws, size_t ws_size,
                              hipStream_t stream) {
    const float* lp = (const float*)d_in[0];
    const int* tgt = (const int*)d_in[1];
    const int* il = (const int*)d_in[2];
    const int* tl = (const int*)d_in[3];
    float* ws = (float*)d_ws;   // [0]=F [1]=Lo [2]=counter

    hipMemsetAsync(ws, 0, 3 * sizeof(float), stream);
    ctc_fused<<<dim3(NBLK), dim3(512), 0, stream>>>(
        lp, tgt, il, tl, ws, (float*)d_out);
}